// Round 2
// baseline (88.750 us; speedup 1.0000x reference)
//
#include <hip/hip_runtime.h>
#include <hip/hip_bf16.h>

typedef __bf16 bf16x8 __attribute__((ext_vector_type(8)));
typedef __bf16 bf16x2 __attribute__((ext_vector_type(2)));
typedef float  f32x16 __attribute__((ext_vector_type(16)));

#define NTOT 8192
#define DDIM 128
#define HALFB 4096
#define CSPLIT 32
#define COLS_PER_BLK (NTOT / CSPLIT)      // 256
#define TILES_PER_BLK (COLS_PER_BLK / 32) // 8
#define TWO_LOG2E 2.885390081777927f      // 2 / ln(2)

// ---------------- kernel 1: row-normalize to bf16 ----------------
__global__ __launch_bounds__(256) void k_norm(const float* __restrict__ zi,
                                              const float* __restrict__ zj,
                                              __bf16* __restrict__ zh) {
    int wave = threadIdx.x >> 6;
    int lane = threadIdx.x & 63;
    int row  = blockIdx.x * 4 + wave;
    const float* src = (row < HALFB) ? (zi + (size_t)row * DDIM)
                                     : (zj + (size_t)(row - HALFB) * DDIM);
    float2 v = *(const float2*)(src + lane * 2);
    float ss = v.x * v.x + v.y * v.y;
    #pragma unroll
    for (int m = 1; m < 64; m <<= 1) ss += __shfl_xor(ss, m, 64);
    float norm = sqrtf(ss);
    float inv  = 1.0f / fmaxf(norm, 1e-8f);
    bf16x2 o;
    o[0] = (__bf16)(v.x * inv);
    o[1] = (__bf16)(v.y * inv);
    *(bf16x2*)(zh + (size_t)row * DDIM + lane * 2) = o;
}

// ---------------- kernel 2: fused sim + exp-sum + pos capture ----------------
// block = 4 waves; wave w owns rows [rowbase, rowbase+32); all 4 waves sweep
// the same 256-column slice. A fragments live in registers for the kernel.
__global__ __launch_bounds__(256) void k_sim(const __bf16* __restrict__ zh,
                                             float* __restrict__ part,
                                             float* __restrict__ posv) {
    int wave = threadIdx.x >> 6;
    int lane = threadIdx.x & 63;
    int rowgroup = blockIdx.x / CSPLIT;
    int colblk   = blockIdx.x & (CSPLIT - 1);
    int rowbase  = rowgroup * 128 + wave * 32;
    int colstart = colblk * COLS_PER_BLK;
    int l31   = lane & 31;
    int kbase = (lane >> 5) * 8;
    int hi4   = (lane >> 5) * 4;

    bf16x8 afrag[8];
    const __bf16* ap = zh + (size_t)(rowbase + l31) * DDIM + kbase;
    #pragma unroll
    for (int kk = 0; kk < 8; kk++)
        afrag[kk] = *(const bf16x8*)(ap + kk * 16);

    float sumexp[16];
    #pragma unroll
    for (int r = 0; r < 16; r++) sumexp[r] = 0.0f;

    for (int t = 0; t < TILES_PER_BLK; t++) {
        int cbase = colstart + t * 32;
        const __bf16* bp = zh + (size_t)(cbase + l31) * DDIM + kbase;
        bf16x8 bfrag[8];
        #pragma unroll
        for (int kk = 0; kk < 8; kk++)
            bfrag[kk] = *(const bf16x8*)(bp + kk * 16);

        f32x16 acc = {0.f,0.f,0.f,0.f,0.f,0.f,0.f,0.f,
                      0.f,0.f,0.f,0.f,0.f,0.f,0.f,0.f};
        #pragma unroll
        for (int kk = 0; kk < 8; kk++)
            acc = __builtin_amdgcn_mfma_f32_32x32x16_bf16(afrag[kk], bfrag[kk], acc, 0, 0, 0);

        if (cbase == rowbase) {
            // diagonal tile: exclude j == i
            #pragma unroll
            for (int r = 0; r < 16; r++) {
                int rl = (r & 3) + 8 * (r >> 2) + hi4;
                float e = __builtin_amdgcn_exp2f(acc[r] * TWO_LOG2E);
                sumexp[r] += (rl == l31) ? 0.0f : e;
            }
        } else if (cbase == (rowbase ^ HALFB)) {
            // positive tile: capture sim[i, i^B] (owning lane writes direct)
            #pragma unroll
            for (int r = 0; r < 16; r++) {
                int rl = (r & 3) + 8 * (r >> 2) + hi4;
                sumexp[r] += __builtin_amdgcn_exp2f(acc[r] * TWO_LOG2E);
                if (rl == l31) posv[rowbase + rl] = acc[r] * 2.0f;
            }
        } else {
            #pragma unroll
            for (int r = 0; r < 16; r++)
                sumexp[r] += __builtin_amdgcn_exp2f(acc[r] * TWO_LOG2E);
        }
    }

    // reduce sumexp across the 32-lane column groups (halves stay separate)
    #pragma unroll
    for (int m = 1; m < 32; m <<= 1) {
        #pragma unroll
        for (int r = 0; r < 16; r++)
            sumexp[r] += __shfl_xor(sumexp[r], m, 64);
    }

    if (l31 == 0) {
        #pragma unroll
        for (int r = 0; r < 16; r++) {
            int rl  = (r & 3) + 8 * (r >> 2) + hi4;
            int row = rowbase + rl;
            part[(size_t)row * CSPLIT + colblk] = sumexp[r];
        }
    }
}

// ---------------- kernel 3: per-row loss + per-block partial sum ----------------
__global__ __launch_bounds__(256) void k_row(const float* __restrict__ part,
                                             const float* __restrict__ posv,
                                             float* __restrict__ bsum) {
    int row = blockIdx.x * 256 + threadIdx.x;
    float se = 0.0f;
    #pragma unroll
    for (int c = 0; c < CSPLIT; c++) se += part[(size_t)row * CSPLIT + c];
    float loss = __logf(se) - posv[row];
    #pragma unroll
    for (int m = 1; m < 64; m <<= 1) loss += __shfl_xor(loss, m, 64);
    __shared__ float ws[4];
    int wave = threadIdx.x >> 6, lane = threadIdx.x & 63;
    if (lane == 0) ws[wave] = loss;
    __syncthreads();
    if (threadIdx.x == 0)
        bsum[blockIdx.x] = ws[0] + ws[1] + ws[2] + ws[3];
}

// ---------------- kernel 4: final deterministic reduce + mean ----------------
__global__ void k_fin(const float* __restrict__ bsum, float* __restrict__ out) {
    int lane = threadIdx.x;  // 64 threads
    float v = (lane < 32) ? bsum[lane] : 0.0f;
    #pragma unroll
    for (int m = 1; m < 64; m <<= 1) v += __shfl_xor(v, m, 64);
    if (lane == 0) out[0] = v * (1.0f / NTOT);
}

extern "C" void kernel_launch(void* const* d_in, const int* in_sizes, int n_in,
                              void* d_out, int out_size, void* d_ws, size_t ws_size,
                              hipStream_t stream) {
    const float* zi = (const float*)d_in[0];
    const float* zj = (const float*)d_in[1];
    char* ws = (char*)d_ws;
    __bf16* zh   = (__bf16*)ws;                                   // 2 MB
    float*  part = (float*)(ws + (size_t)NTOT * DDIM * 2);        // 1 MB
    float*  posv = (float*)((char*)part + (size_t)NTOT * CSPLIT * sizeof(float)); // 32 KB
    float*  bsum = (float*)((char*)posv + (size_t)NTOT * sizeof(float));

    hipLaunchKernelGGL(k_norm, dim3(NTOT / 4), dim3(256), 0, stream, zi, zj, zh);
    hipLaunchKernelGGL(k_sim,  dim3((NTOT / 128) * CSPLIT), dim3(256), 0, stream, zh, part, posv);
    hipLaunchKernelGGL(k_row,  dim3(NTOT / 256), dim3(256), 0, stream, part, posv, bsum);
    hipLaunchKernelGGL(k_fin,  dim3(1), dim3(64), 0, stream, bsum, (float*)d_out);
}

// Round 4
// 40.664 us; speedup vs baseline: 2.1825x; 2.1825x over previous
//
#include <hip/hip_runtime.h>
#include <hip/hip_bf16.h>

typedef __bf16 bf16x8 __attribute__((ext_vector_type(8)));
typedef __bf16 bf16x2 __attribute__((ext_vector_type(2)));
typedef float  f32x16 __attribute__((ext_vector_type(16)));

#define NTOT 8192
#define DDIM 128
#define HALFB 4096
#define CSPLIT 16
#define COLS_PER_BLK (NTOT / CSPLIT)      // 512
#define TILES_PER_BLK (COLS_PER_BLK / 32) // 16

// ---------------- kernel 1: row-normalize to bf16 ----------------
__global__ __launch_bounds__(256) void k_norm(const float* __restrict__ zi,
                                              const float* __restrict__ zj,
                                              __bf16* __restrict__ zh) {
    int wave = threadIdx.x >> 6;
    int lane = threadIdx.x & 63;
    int row  = blockIdx.x * 4 + wave;
    const float* src = (row < HALFB) ? (zi + (size_t)row * DDIM)
                                     : (zj + (size_t)(row - HALFB) * DDIM);
    float2 v = *(const float2*)(src + lane * 2);
    float ss = v.x * v.x + v.y * v.y;
    #pragma unroll
    for (int m = 1; m < 64; m <<= 1) ss += __shfl_xor(ss, m, 64);
    float norm = sqrtf(ss);
    float inv  = 1.0f / fmaxf(norm, 1e-8f);
    bf16x2 o;
    o[0] = (__bf16)(v.x * inv);
    o[1] = (__bf16)(v.y * inv);
    *(bf16x2*)(zh + (size_t)row * DDIM + lane * 2) = o;
}

// ---------------- kernel 2: fused sim + exp-sum + pos capture ----------------
// Block = 4 waves x 64 rows = 256 rows; all waves sweep the same 512-col slice.
// B tile (32 cols x 128 k) staged in LDS in FRAGMENT order via explicit
// reg-staging: wave w gathers chunks c=2w,2w+1; lane writes its own 16B at
// bbuf[c*1024 + lane*16]; reads are lane-contiguous ds_read_b128.
__global__ __launch_bounds__(256, 2) void k_sim(const __bf16* __restrict__ zh,
                                                float* __restrict__ part,
                                                float* __restrict__ posv) {
    __shared__ char bbuf[8192] __attribute__((aligned(16)));

    int wave = threadIdx.x >> 6;
    int lane = threadIdx.x & 63;
    int rowgroup = blockIdx.x / CSPLIT;
    int colblk   = blockIdx.x & (CSPLIT - 1);
    int rowbase  = rowgroup * 256 + wave * 64;   // this wave's first row
    int colstart = colblk * COLS_PER_BLK;
    int l31   = lane & 31;
    int kbase = (lane >> 5) * 8;
    int hi4   = (lane >> 5) * 4;

    const char* zhb = (const char*)zh;

    // A fragments: 64 rows, held in registers for the whole kernel
    bf16x8 afrag[2][8];
    #pragma unroll
    for (int h = 0; h < 2; h++) {
        const __bf16* ap = zh + (size_t)(rowbase + 32 * h + l31) * DDIM + kbase;
        #pragma unroll
        for (int kk = 0; kk < 8; kk++)
            afrag[h][kk] = *(const bf16x8*)(ap + kk * 16);
    }

    float sumexp[2][16];
    #pragma unroll
    for (int h = 0; h < 2; h++)
        #pragma unroll
        for (int r = 0; r < 16; r++) sumexp[h][r] = 0.0f;

    // staging: wave w owns chunks kk0, kk0+1. For column-tile base cbase,
    // chunk c, lane l fetches global bytes
    //   (cbase + (l&31))*256 + (l>>5)*16 + c*32   (= fragment c of col l&31)
    int kk0 = 2 * wave;
    const char* gl = zhb + (size_t)l31 * 256 + ((lane >> 5) * 16) + kk0 * 32;
    char* wr0 = bbuf + kk0 * 1024 + lane * 16;
    char* wr1 = wr0 + 1024;

    uint4 st0 = *(const uint4*)(gl + (size_t)colstart * 256);
    uint4 st1 = *(const uint4*)(gl + (size_t)colstart * 256 + 32);

    for (int t = 0; t < TILES_PER_BLK; t++) {
        int cbase = colstart + t * 32;
        __syncthreads();                 // previous tile's LDS reads complete
        *(uint4*)wr0 = st0;
        *(uint4*)wr1 = st1;
        __syncthreads();                 // staged tile visible to all waves
        if (t + 1 < TILES_PER_BLK) {     // issue next-tile gathers early
            st0 = *(const uint4*)(gl + (size_t)(cbase + 32) * 256);
            st1 = *(const uint4*)(gl + (size_t)(cbase + 32) * 256 + 32);
        }

        // fragment reads: lane-contiguous b128, conflict-free
        bf16x8 bfrag[8];
        const char* bb = bbuf + lane * 16;
        #pragma unroll
        for (int kk = 0; kk < 8; kk++)
            bfrag[kk] = *(const bf16x8*)(bb + kk * 1024);

        f32x16 acc0 = {0.f,0.f,0.f,0.f,0.f,0.f,0.f,0.f,
                       0.f,0.f,0.f,0.f,0.f,0.f,0.f,0.f};
        f32x16 acc1 = acc0;
        #pragma unroll
        for (int kk = 0; kk < 8; kk++) {
            acc0 = __builtin_amdgcn_mfma_f32_32x32x16_bf16(afrag[0][kk], bfrag[kk], acc0, 0, 0, 0);
            acc1 = __builtin_amdgcn_mfma_f32_32x32x16_bf16(afrag[1][kk], bfrag[kk], acc1, 0, 0, 0);
        }

        #pragma unroll
        for (int h = 0; h < 2; h++) {
            const f32x16& acc = h ? acc1 : acc0;
            int myrowbase = rowbase + 32 * h;
            if (cbase == myrowbase) {
                // diagonal tile: exclude j == i
                #pragma unroll
                for (int r = 0; r < 16; r++) {
                    int rl = (r & 3) + 8 * (r >> 2) + hi4;
                    float e = __expf(acc[r] * 2.0f);
                    sumexp[h][r] += (rl == l31) ? 0.0f : e;
                }
            } else if (cbase == (myrowbase ^ HALFB)) {
                // positive tile: owning lane writes pos directly
                #pragma unroll
                for (int r = 0; r < 16; r++) {
                    int rl = (r & 3) + 8 * (r >> 2) + hi4;
                    sumexp[h][r] += __expf(acc[r] * 2.0f);
                    if (rl == l31) posv[myrowbase + rl] = acc[r] * 2.0f;
                }
            } else {
                #pragma unroll
                for (int r = 0; r < 16; r++)
                    sumexp[h][r] += __expf(acc[r] * 2.0f);
            }
        }
    }

    // reduce across the 32-lane column groups (halves stay separate: masks < 32)
    #pragma unroll
    for (int m = 1; m < 32; m <<= 1)
        #pragma unroll
        for (int h = 0; h < 2; h++)
            #pragma unroll
            for (int r = 0; r < 16; r++)
                sumexp[h][r] += __shfl_xor(sumexp[h][r], m, 64);

    if (l31 == 0) {
        #pragma unroll
        for (int h = 0; h < 2; h++)
            #pragma unroll
            for (int r = 0; r < 16; r++) {
                int rl  = (r & 3) + 8 * (r >> 2) + hi4;
                int row = rowbase + 32 * h + rl;
                part[(size_t)row * CSPLIT + colblk] = sumexp[h][r];
            }
    }
}

// ---------------- kernel 3: per-row loss + per-block partial sum ----------------
__global__ __launch_bounds__(256) void k_row(const float* __restrict__ part,
                                             const float* __restrict__ posv,
                                             float* __restrict__ bsum) {
    int row = blockIdx.x * 256 + threadIdx.x;
    float se = 0.0f;
    #pragma unroll
    for (int c = 0; c < CSPLIT; c++) se += part[(size_t)row * CSPLIT + c];
    float loss = __logf(se) - posv[row];
    #pragma unroll
    for (int m = 1; m < 64; m <<= 1) loss += __shfl_xor(loss, m, 64);
    __shared__ float ws[4];
    int wave = threadIdx.x >> 6, lane = threadIdx.x & 63;
    if (lane == 0) ws[wave] = loss;
    __syncthreads();
    if (threadIdx.x == 0)
        bsum[blockIdx.x] = ws[0] + ws[1] + ws[2] + ws[3];
}

// ---------------- kernel 4: final deterministic reduce + mean ----------------
__global__ void k_fin(const float* __restrict__ bsum, float* __restrict__ out) {
    int lane = threadIdx.x;  // 64 threads
    float v = (lane < 32) ? bsum[lane] : 0.0f;
    #pragma unroll
    for (int m = 1; m < 64; m <<= 1) v += __shfl_xor(v, m, 64);
    if (lane == 0) out[0] = v * (1.0f / NTOT);
}

extern "C" void kernel_launch(void* const* d_in, const int* in_sizes, int n_in,
                              void* d_out, int out_size, void* d_ws, size_t ws_size,
                              hipStream_t stream) {
    const float* zi = (const float*)d_in[0];
    const float* zj = (const float*)d_in[1];
    char* ws = (char*)d_ws;
    __bf16* zh   = (__bf16*)ws;                                   // 2 MB
    float*  part = (float*)(ws + (size_t)NTOT * DDIM * 2);        // 512 KB
    float*  posv = (float*)((char*)part + (size_t)NTOT * CSPLIT * sizeof(float)); // 32 KB
    float*  bsum = (float*)((char*)posv + (size_t)NTOT * sizeof(float));

    hipLaunchKernelGGL(k_norm, dim3(NTOT / 4), dim3(256), 0, stream, zi, zj, zh);
    hipLaunchKernelGGL(k_sim,  dim3((NTOT / 256) * CSPLIT), dim3(256), 0, stream, zh, part, posv);
    hipLaunchKernelGGL(k_row,  dim3(NTOT / 256), dim3(256), 0, stream, part, posv, bsum);
    hipLaunchKernelGGL(k_fin,  dim3(1), dim3(64), 0, stream, bsum, (float*)d_out);
}

// Round 5
// 39.834 us; speedup vs baseline: 2.2280x; 1.0208x over previous
//
#include <hip/hip_runtime.h>
#include <hip/hip_bf16.h>

typedef __bf16 bf16x8 __attribute__((ext_vector_type(8)));
typedef __bf16 bf16x2 __attribute__((ext_vector_type(2)));
typedef float  f32x16 __attribute__((ext_vector_type(16)));

#define NTOT 8192
#define DDIM 128
#define HALFB 4096
#define CSPLIT 16
#define COLS_PER_BLK (NTOT / CSPLIT)      // 512
#define TILES_PER_BLK (COLS_PER_BLK / 64) // 8 tiles of 64 cols

// ---------------- kernel 1: row-normalize to bf16 ----------------
__global__ __launch_bounds__(256) void k_norm(const float* __restrict__ zi,
                                              const float* __restrict__ zj,
                                              __bf16* __restrict__ zh) {
    int wave = threadIdx.x >> 6;
    int lane = threadIdx.x & 63;
    int row  = blockIdx.x * 4 + wave;
    const float* src = (row < HALFB) ? (zi + (size_t)row * DDIM)
                                     : (zj + (size_t)(row - HALFB) * DDIM);
    float2 v = *(const float2*)(src + lane * 2);
    float ss = v.x * v.x + v.y * v.y;
    #pragma unroll
    for (int m = 1; m < 64; m <<= 1) ss += __shfl_xor(ss, m, 64);
    float norm = sqrtf(ss);
    float inv  = 1.0f / fmaxf(norm, 1e-8f);
    bf16x2 o;
    o[0] = (__bf16)(v.x * inv);
    o[1] = (__bf16)(v.y * inv);
    *(bf16x2*)(zh + (size_t)row * DDIM + lane * 2) = o;
}

// ---------------- kernel 2: fused sim + exp-sum + pos capture ----------------
// Block = 4 waves x 64 rows = 256 rows; all waves sweep the same 512-col slice.
// Tile = 64 cols x 128 k (16 KB), double-buffered in LDS, ONE barrier per tile.
// Fragment-order staging: chunk kk (1 KB) holds frag (kk&7) of cols
// [cg*32,cg*32+32), cg=kk>>3; lane writes its own 16B at buf+kk*1024+lane*16.
__global__ __launch_bounds__(256, 2) void k_sim(const __bf16* __restrict__ zh,
                                                float* __restrict__ part,
                                                float* __restrict__ posv) {
    __shared__ char bbuf[2][16384] __attribute__((aligned(16)));

    int wave = threadIdx.x >> 6;
    int lane = threadIdx.x & 63;
    int rowgroup = blockIdx.x / CSPLIT;
    int colblk   = blockIdx.x & (CSPLIT - 1);
    int rowbase  = rowgroup * 256 + wave * 64;   // this wave's first row
    int colstart = colblk * COLS_PER_BLK;
    int l31   = lane & 31;
    int kbase = (lane >> 5) * 8;
    int hi4   = (lane >> 5) * 4;

    const char* zhb = (const char*)zh;

    // A fragments: 64 rows, in registers for the whole kernel
    bf16x8 afrag[2][8];
    #pragma unroll
    for (int h = 0; h < 2; h++) {
        const __bf16* ap = zh + (size_t)(rowbase + 32 * h + l31) * DDIM + kbase;
        #pragma unroll
        for (int kk = 0; kk < 8; kk++)
            afrag[h][kk] = *(const bf16x8*)(ap + kk * 16);
    }

    float sumexp[2][16];
    #pragma unroll
    for (int h = 0; h < 2; h++)
        #pragma unroll
        for (int r = 0; r < 16; r++) sumexp[h][r] = 0.0f;

    // staging: wave w owns chunks kk = 4w..4w+3  (cg = w>>1, s = 4(w&1)+j)
    int kkbase = 4 * wave;
    int cgw    = wave >> 1;            // which 32-col group this wave stages
    int s0     = 4 * (wave & 1);       // first sub-chunk (fragment) index
    // per-lane global byte offset within a (cg,s) chunk:
    //   col (cg*32 + l31) -> row byte (l31)*256 ; frag s half (l>>5)*16 + s*32
    const char* gl = zhb + (size_t)l31 * 256 + ((lane >> 5) * 16) + s0 * 32
                         + (size_t)cgw * 32 * 256;
    char* wr = (char*)bbuf + (size_t)kkbase * 1024 + lane * 16;  // into bbuf[0]

    uint4 st0, st1, st2, st3;
    {
        const char* g = gl + (size_t)colstart * 256;
        st0 = *(const uint4*)(g);
        st1 = *(const uint4*)(g + 32);
        st2 = *(const uint4*)(g + 64);
        st3 = *(const uint4*)(g + 96);
    }
    *(uint4*)(wr)        = st0;
    *(uint4*)(wr + 1024) = st1;
    *(uint4*)(wr + 2048) = st2;
    *(uint4*)(wr + 3072) = st3;
    __syncthreads();

    int cur = 0;
    for (int t = 0; t < TILES_PER_BLK; t++) {
        int tbase = colstart + t * 64;
        // issue next tile's gathers first (latency hides under MFMA+exp)
        if (t + 1 < TILES_PER_BLK) {
            const char* g = gl + (size_t)(tbase + 64) * 256;
            st0 = *(const uint4*)(g);
            st1 = *(const uint4*)(g + 32);
            st2 = *(const uint4*)(g + 64);
            st3 = *(const uint4*)(g + 96);
        }

        #pragma unroll
        for (int cg = 0; cg < 2; cg++) {
            int cbase = tbase + cg * 32;
            bf16x8 bfrag[8];
            const char* bb = bbuf[cur] + cg * 8192 + lane * 16;
            #pragma unroll
            for (int kk = 0; kk < 8; kk++)
                bfrag[kk] = *(const bf16x8*)(bb + kk * 1024);

            f32x16 acc0 = {0.f,0.f,0.f,0.f,0.f,0.f,0.f,0.f,
                           0.f,0.f,0.f,0.f,0.f,0.f,0.f,0.f};
            f32x16 acc1 = acc0;
            #pragma unroll
            for (int kk = 0; kk < 8; kk++) {
                acc0 = __builtin_amdgcn_mfma_f32_32x32x16_bf16(afrag[0][kk], bfrag[kk], acc0, 0, 0, 0);
                acc1 = __builtin_amdgcn_mfma_f32_32x32x16_bf16(afrag[1][kk], bfrag[kk], acc1, 0, 0, 0);
            }

            #pragma unroll
            for (int h = 0; h < 2; h++) {
                const f32x16& acc = h ? acc1 : acc0;
                int myrowbase = rowbase + 32 * h;
                if (cbase == myrowbase) {
                    // diagonal tile: exclude j == i
                    #pragma unroll
                    for (int r = 0; r < 16; r++) {
                        int rl = (r & 3) + 8 * (r >> 2) + hi4;
                        float e = __expf(acc[r] * 2.0f);
                        sumexp[h][r] += (rl == l31) ? 0.0f : e;
                    }
                } else if (cbase == (myrowbase ^ HALFB)) {
                    // positive tile: owning lane writes pos directly
                    #pragma unroll
                    for (int r = 0; r < 16; r++) {
                        int rl = (r & 3) + 8 * (r >> 2) + hi4;
                        sumexp[h][r] += __expf(acc[r] * 2.0f);
                        if (rl == l31) posv[myrowbase + rl] = acc[r] * 2.0f;
                    }
                } else {
                    #pragma unroll
                    for (int r = 0; r < 16; r++)
                        sumexp[h][r] += __expf(acc[r] * 2.0f);
                }
            }
        }

        // write next tile into the other buffer; one barrier ends the tile
        if (t + 1 < TILES_PER_BLK) {
            char* w = (char*)bbuf + (size_t)(cur ^ 1) * 16384
                                  + (size_t)kkbase * 1024 + lane * 16;
            *(uint4*)(w)        = st0;
            *(uint4*)(w + 1024) = st1;
            *(uint4*)(w + 2048) = st2;
            *(uint4*)(w + 3072) = st3;
            __syncthreads();
            cur ^= 1;
        }
    }

    // reduce across the 32-lane column groups (halves stay separate: masks < 32)
    #pragma unroll
    for (int m = 1; m < 32; m <<= 1)
        #pragma unroll
        for (int h = 0; h < 2; h++)
            #pragma unroll
            for (int r = 0; r < 16; r++)
                sumexp[h][r] += __shfl_xor(sumexp[h][r], m, 64);

    if (l31 == 0) {
        #pragma unroll
        for (int h = 0; h < 2; h++)
            #pragma unroll
            for (int r = 0; r < 16; r++) {
                int rl  = (r & 3) + 8 * (r >> 2) + hi4;
                int row = rowbase + 32 * h + rl;
                part[(size_t)row * CSPLIT + colblk] = sumexp[h][r];
            }
    }
}

// ---------------- kernel 3: per-row loss + per-block partial sum ----------------
__global__ __launch_bounds__(256) void k_row(const float* __restrict__ part,
                                             const float* __restrict__ posv,
                                             float* __restrict__ bsum) {
    int row = blockIdx.x * 256 + threadIdx.x;
    float se = 0.0f;
    #pragma unroll
    for (int c = 0; c < CSPLIT; c++) se += part[(size_t)row * CSPLIT + c];
    float loss = __logf(se) - posv[row];
    #pragma unroll
    for (int m = 1; m < 64; m <<= 1) loss += __shfl_xor(loss, m, 64);
    __shared__ float ws[4];
    int wave = threadIdx.x >> 6, lane = threadIdx.x & 63;
    if (lane == 0) ws[wave] = loss;
    __syncthreads();
    if (threadIdx.x == 0)
        bsum[blockIdx.x] = ws[0] + ws[1] + ws[2] + ws[3];
}

// ---------------- kernel 4: final deterministic reduce + mean ----------------
__global__ void k_fin(const float* __restrict__ bsum, float* __restrict__ out) {
    int lane = threadIdx.x;  // 64 threads
    float v = (lane < 32) ? bsum[lane] : 0.0f;
    #pragma unroll
    for (int m = 1; m < 64; m <<= 1) v += __shfl_xor(v, m, 64);
    if (lane == 0) out[0] = v * (1.0f / NTOT);
}

extern "C" void kernel_launch(void* const* d_in, const int* in_sizes, int n_in,
                              void* d_out, int out_size, void* d_ws, size_t ws_size,
                              hipStream_t stream) {
    const float* zi = (const float*)d_in[0];
    const float* zj = (const float*)d_in[1];
    char* ws = (char*)d_ws;
    __bf16* zh   = (__bf16*)ws;                                   // 2 MB
    float*  part = (float*)(ws + (size_t)NTOT * DDIM * 2);        // 512 KB
    float*  posv = (float*)((char*)part + (size_t)NTOT * CSPLIT * sizeof(float)); // 32 KB
    float*  bsum = (float*)((char*)posv + (size_t)NTOT * sizeof(float));

    hipLaunchKernelGGL(k_norm, dim3(NTOT / 4), dim3(256), 0, stream, zi, zj, zh);
    hipLaunchKernelGGL(k_sim,  dim3((NTOT / 256) * CSPLIT), dim3(256), 0, stream, zh, part, posv);
    hipLaunchKernelGGL(k_row,  dim3(NTOT / 256), dim3(256), 0, stream, part, posv, bsum);
    hipLaunchKernelGGL(k_fin,  dim3(1), dim3(64), 0, stream, bsum, (float*)d_out);
}